// Round 13
// baseline (325.153 us; speedup 1.0000x reference)
//
#include <hip/hip_runtime.h>
#include <hip/hip_bf16.h>

// C3 partial connection via MFMA (fp16 in / fp32 acc), wave-independent form.
// y = conv5x5(channel-subsets) + bias; out = 1.7159*tanh(2/3*y).
// M = 16 consecutive x-pixels, N = 16 output channels, K = dx*8 + c (c pad 6->8),
// two mfma_f32_16x16x32_f16 per (row, dy): m=0 dx0..3, m=1 dx4 (rest zero-wt).
//
// R13 = R12 geometry (wave stages 36px x 16 rows, computes 32px x 12 rows)
// with: (1) per-row-pair INTERLEAVED tiles -> both 64B halves of each 128B
// output line stored back-to-back (L2 merge; R12 wrote them ~2us apart and
// WRITE blew up to 547MB); (2) no W6 ring - scoped per-pair frag loads (LDS
// has headroom); (3) two-phase staging (9+9 items) to keep transient VGPR at
// R11's class -> occupancy back to ~50% (R12's 72-reg batch gave 39%).
// Retained: batched-within-phase staging, 2-wave blocks, setprio, XCD swizzle.

#define IH 142
#define IW 142
#define OH 138
#define OW 138
#define WROWS 12        // output rows per wave
#define SROWS 16        // staged input rows per wave
#define RS_H  288       // halfs per staged row (36 px * 8 ch)
#define RS_D  144       // dwords per staged row
#define WV_HALFS (SROWS * RS_H + 32)  // + zeroed tail pad (m=1 overrun, zero-wt)
#define NTILE_X 5
#define NTILE_Y 6
#define NWG (NTILE_X * NTILE_Y * 256)   // 7680, divisible by 8
#define CPX (NWG / 8)                   // 960 tiles per XCD

typedef _Float16 f16x8 __attribute__((ext_vector_type(8)));
typedef float f32x4 __attribute__((ext_vector_type(4)));

// WIDX[oc][c] = src*64 + block-index, or -1. src 0=w3(6,3,5,5) 1=w4(9,4,5,5)
// 2=w6(1,6,5,5); weight elem = blk*25 + dy*5 + dx.
__device__ __constant__ const short WIDX16[16][6] = {
  {   0,    1,    2,   -1,   -1,   -1},   // oc0  {0,1,2}
  {  -1,    3,    4,    5,   -1,   -1},   // oc1  {1,2,3}
  {  -1,   -1,    6,    7,    8,   -1},   // oc2  {2,3,4}
  {  -1,   -1,   -1,    9,   10,   11},   // oc3  {3,4,5}
  {  12,   -1,   -1,   -1,   13,   14},   // oc4  {0,4,5}
  {  15,   16,   -1,   -1,   -1,   17},   // oc5  {0,1,5}
  {64+0, 64+1, 64+2, 64+3,   -1,   -1},   // oc6  {0,1,2,3}
  {  -1, 64+4, 64+5, 64+6, 64+7,   -1},   // oc7  {1,2,3,4}
  {  -1,   -1, 64+8, 64+9, 64+10, 64+11}, // oc8  {2,3,4,5}
  {64+12,  -1,   -1, 64+13, 64+14, 64+15},// oc9  {0,3,4,5}
  {64+16, 64+17, -1,   -1, 64+18, 64+19}, // oc10 {0,1,4,5}
  {64+20, 64+21, 64+22, -1,  -1, 64+23},  // oc11 {0,1,2,5}
  {64+24, 64+25, -1, 64+26, 64+27,  -1},  // oc12 {0,1,3,4}
  {  -1, 64+28, 64+29, -1, 64+30, 64+31}, // oc13 {1,2,4,5}
  {64+32,  -1, 64+33, 64+34, -1, 64+35},  // oc14 {0,2,3,5}
  {128+0, 128+1, 128+2, 128+3, 128+4, 128+5}, // oc15 {0..5}
};

// prep: per-lane pre-swizzled B fragments, 5 dy x 2 m x 64 lanes x 8 halfs.
__global__ void wprep_kernel(const float* __restrict__ w3, const float* __restrict__ w4,
                             const float* __restrict__ w6, _Float16* __restrict__ tab) {
  int t = blockIdx.x * 256 + threadIdx.x;
  if (t >= 5120) return;
  int j = t & 7, lane = (t >> 3) & 63, dm = t >> 9;
  int dy = dm >> 1, m = dm & 1;
  int q = lane >> 4, oc = lane & 15;
  int k = m * 32 + q * 8 + j;
  int dx = k >> 3, c = k & 7;
  float v = 0.f;
  if (c < 6 && dx < 5) {
    int e = WIDX16[oc][c];
    if (e >= 0) {
      int src = e >> 6, blk = e & 63;
      const float* wp = (src == 0) ? w3 : (src == 1) ? w4 : w6;
      v = wp[blk * 25 + dy * 5 + dx];
    }
  }
  tab[t] = (_Float16)v;
}

__device__ __forceinline__ unsigned int pkh(float a, float b) {
  _Float16 ha = (_Float16)a, hb = (_Float16)b;
  unsigned short ua = __builtin_bit_cast(unsigned short, ha);
  unsigned short ub = __builtin_bit_cast(unsigned short, hb);
  return (unsigned int)ua | ((unsigned int)ub << 16);
}

__device__ __forceinline__ float act(float y) {
  const float TS = 1.9235933878519512f;  // 2*(2/3)*log2(e)
  const float e = __builtin_amdgcn_exp2f(y * TS);
  return fmaf(-2.f * 1.7159f, __builtin_amdgcn_rcpf(e + 1.f), 1.7159f);
}

// Block: 128 threads = 2 independent waves; wave w -> rows y0+w*12..+11, 32 px.
// Logical grid: (5 x-tiles of 32 px, 6 y-slabs of 24 rows, 256 images),
// XCD-chunk-swizzled.
__global__ __launch_bounds__(128, 4)
void c3_mfma(const float* __restrict__ x,
             const float* __restrict__ b3, const float* __restrict__ b4,
             const float* __restrict__ b6, const _Float16* __restrict__ tab,
             float* __restrict__ out) {
  __shared__ __attribute__((aligned(16))) _Float16 sh[2 * WV_HALFS];  // 18560 B

  const int tid  = threadIdx.x;
  const int lane = tid & 63;
  const int w    = tid >> 6;   // 0..1

  // ---- chunked XCD swizzle ----
  const int hwid = (int)blockIdx.x + NTILE_X * ((int)blockIdx.y + NTILE_Y * (int)blockIdx.z);
  const int swz  = (hwid & 7) * CPX + (hwid >> 3);
  const int tx   = swz % NTILE_X;
  const int t2   = swz / NTILE_X;
  const int ty   = t2 % NTILE_Y;
  const int b    = t2 / NTILE_Y;

  const int x0   = min(tx * 32, OW - 32);  // {0,32,64,96,106}
  const int y0   = min(ty * 24, OH - 24);  // {0,24,48,72,96,114}
  const int ry0  = y0 + w * WROWS;         // wave's first row

  const int ocl = lane & 15;
  const int qq  = lane >> 4;

  const float* xb = x + (size_t)b * 6 * IH * IW;
  _Float16* __restrict__ shw = sh + w * WV_HALFS;
  unsigned int* __restrict__ shu = (unsigned int*)shw;
  if (lane < 16) shu[SROWS * RS_D + lane] = 0u;   // zero tail pad

  // ---- staging phase A: items 0..8 (channels 0..3), 18 loads in flight ----
  float2 va[9], vb[9];
  #pragma unroll
  for (int it = 0; it < 9; ++it) {
    const int idx = it * 64 + lane;          // ic2(4) x row(16) x px2(18)
    const int ic2 = idx / 288;
    const int rem = idx - ic2 * 288;
    const int row = rem / 18;
    const int px2 = rem - row * 18;
    if (ic2 < 3) {
      const float* pa = xb + ((size_t)(2 * ic2) * IH + (ry0 + row)) * IW + x0 + 2 * px2;
      va[it] = *(const float2*)pa;
      vb[it] = *(const float2*)(pa + (size_t)IH * IW);
    }
  }

  // ---- B fragments + bias: independent, overlap phase-A latency ----
  f16x8 Bf[5][2];
  #pragma unroll
  for (int dy = 0; dy < 5; ++dy)
    #pragma unroll
    for (int m = 0; m < 2; ++m)
      Bf[dy][m] = *(const f16x8*)(tab + ((size_t)((dy * 2 + m) * 64 + lane)) * 8);

  const float bv = (ocl < 6) ? b3[ocl] : (ocl < 15) ? b4[ocl - 6] : b6[0];

  // ---- pack phase A ----
  #pragma unroll
  for (int it = 0; it < 9; ++it) {
    const int idx = it * 64 + lane;
    const int ic2 = idx / 288;
    const int rem = idx - ic2 * 288;
    const int row = rem / 18;
    const int px2 = rem - row * 18;
    const int ha  = row * RS_D + px2 * 8 + ic2;
    if (ic2 < 3) {
      shu[ha]     = pkh(va[it].x, vb[it].x);
      shu[ha + 4] = pkh(va[it].y, vb[it].y);
    } else {
      shu[ha]     = 0u;
      shu[ha + 4] = 0u;
    }
  }

  // ---- staging phase B: items 9..17 (channels 4,5 + pad) ----
  #pragma unroll
  for (int it = 0; it < 9; ++it) {
    const int idx = (it + 9) * 64 + lane;
    const int ic2 = idx / 288;
    const int rem = idx - ic2 * 288;
    const int row = rem / 18;
    const int px2 = rem - row * 18;
    if (ic2 < 3) {
      const float* pa = xb + ((size_t)(2 * ic2) * IH + (ry0 + row)) * IW + x0 + 2 * px2;
      va[it] = *(const float2*)pa;
      vb[it] = *(const float2*)(pa + (size_t)IH * IW);
    }
  }
  #pragma unroll
  for (int it = 0; it < 9; ++it) {
    const int idx = (it + 9) * 64 + lane;
    const int ic2 = idx / 288;
    const int rem = idx - ic2 * 288;
    const int row = rem / 18;
    const int px2 = rem - row * 18;
    const int ha  = row * RS_D + px2 * 8 + ic2;
    if (ic2 < 3) {
      shu[ha]     = pkh(va[it].x, vb[it].x);
      shu[ha + 4] = pkh(va[it].y, vb[it].y);
    } else {
      shu[ha]     = 0u;
      shu[ha + 4] = 0u;
    }
  }
  // Wave-level LDS visibility: all 64 lanes' ds_writes complete, no barrier.
  asm volatile("s_waitcnt lgkmcnt(0)" ::: "memory");

  const size_t obase = ((size_t)b * 16 + ocl) * OH;
  const int voff0 = (ocl + qq) * 8;        // tile0; +32 halfs for m=1 (dx+4)
  const int voff1 = voff0 + 128;           // tile1 (+16 px)

  // ---- per row-pair: both tiles computed, then 128B-contiguous stores ----
  #pragma unroll
  for (int r = 0; r < WROWS; r += 2) {
    f32x4 C00 = {bv, bv, bv, bv}, C01 = {bv, bv, bv, bv};
    f32x4 C10 = {bv, bv, bv, bv}, C11 = {bv, bv, bv, bv};

    {  // tile 0
      f16x8 Wp[6][2];
      #pragma unroll
      for (int i = 0; i < 6; ++i) {
        Wp[i][0] = *(const f16x8*)&shw[(r + i) * RS_H + voff0];
        Wp[i][1] = *(const f16x8*)&shw[(r + i) * RS_H + voff0 + 32];
      }
      __builtin_amdgcn_s_setprio(1);
      #pragma unroll
      for (int dy = 0; dy < 5; ++dy) {
        C00 = __builtin_amdgcn_mfma_f32_16x16x32_f16(Wp[dy][0],     Bf[dy][0], C00, 0, 0, 0);
        C01 = __builtin_amdgcn_mfma_f32_16x16x32_f16(Wp[dy + 1][0], Bf[dy][0], C01, 0, 0, 0);
        C00 = __builtin_amdgcn_mfma_f32_16x16x32_f16(Wp[dy][1],     Bf[dy][1], C00, 0, 0, 0);
        C01 = __builtin_amdgcn_mfma_f32_16x16x32_f16(Wp[dy + 1][1], Bf[dy][1], C01, 0, 0, 0);
      }
      __builtin_amdgcn_s_setprio(0);
    }
    {  // tile 1
      f16x8 Wp[6][2];
      #pragma unroll
      for (int i = 0; i < 6; ++i) {
        Wp[i][0] = *(const f16x8*)&shw[(r + i) * RS_H + voff1];
        Wp[i][1] = *(const f16x8*)&shw[(r + i) * RS_H + voff1 + 32];
      }
      __builtin_amdgcn_s_setprio(1);
      #pragma unroll
      for (int dy = 0; dy < 5; ++dy) {
        C10 = __builtin_amdgcn_mfma_f32_16x16x32_f16(Wp[dy][0],     Bf[dy][0], C10, 0, 0, 0);
        C11 = __builtin_amdgcn_mfma_f32_16x16x32_f16(Wp[dy + 1][0], Bf[dy][0], C11, 0, 0, 0);
        C10 = __builtin_amdgcn_mfma_f32_16x16x32_f16(Wp[dy][1],     Bf[dy][1], C10, 0, 0, 0);
        C11 = __builtin_amdgcn_mfma_f32_16x16x32_f16(Wp[dy + 1][1], Bf[dy][1], C11, 0, 0, 0);
      }
      __builtin_amdgcn_s_setprio(0);
    }

    // stores: per oc-row, 32 contiguous px (128 B) issued back-to-back
    {
      float* p0 = out + (obase + (ry0 + r)) * OW + x0 + qq * 4;
      *(float2*)p0        = make_float2(act(C00[0]), act(C00[1]));
      *(float2*)(p0 + 2)  = make_float2(act(C00[2]), act(C00[3]));
      *(float2*)(p0 + 16) = make_float2(act(C10[0]), act(C10[1]));
      *(float2*)(p0 + 18) = make_float2(act(C10[2]), act(C10[3]));
      float* p1 = p0 + OW;
      *(float2*)p1        = make_float2(act(C01[0]), act(C01[1]));
      *(float2*)(p1 + 2)  = make_float2(act(C01[2]), act(C01[3]));
      *(float2*)(p1 + 16) = make_float2(act(C11[0]), act(C11[1]));
      *(float2*)(p1 + 18) = make_float2(act(C11[2]), act(C11[3]));
    }
  }
}

extern "C" void kernel_launch(void* const* d_in, const int* in_sizes, int n_in,
                              void* d_out, int out_size, void* d_ws, size_t ws_size,
                              hipStream_t stream) {
  const float* x  = (const float*)d_in[0];
  const float* w3 = (const float*)d_in[1];
  const float* b3 = (const float*)d_in[2];
  const float* w4 = (const float*)d_in[3];
  const float* b4 = (const float*)d_in[4];
  const float* w6 = (const float*)d_in[5];
  const float* b6 = (const float*)d_in[6];
  float* out = (float*)d_out;
  _Float16* tab = (_Float16*)d_ws;  // 5120 halfs = 10 KiB

  hipLaunchKernelGGL(wprep_kernel, dim3(20), dim3(256), 0, stream, w3, w4, w6, tab);

  dim3 grid(NTILE_X, NTILE_Y, 256);   // x-tiles (32 px), y-slabs (24 rows), batch
  hipLaunchKernelGGL(c3_mfma, grid, dim3(128), 0, stream, x, b3, b4, b6, tab, out);
}

// Round 14
// 157.403 us; speedup vs baseline: 2.0657x; 2.0657x over previous
//
#include <hip/hip_runtime.h>
#include <hip/hip_bf16.h>

// C3 partial connection via MFMA (fp16 in / fp32 acc), full-row-slab form.
// y = conv5x5(channel-subsets) + bias; out = 1.7159*tanh(2/3*y).
// M = 16 px, N = 16 oc, K = dx*8 + c (c pad 6->8); 2 mfma_16x16x32_f16 per
// (row, dy): m=0 dx0..3, m=1 dx4 (dx5..7 zero-weighted).
//
// R14: block (256 thr / 4 waves) owns a FULL-WIDTH 12-row slab. Cooperative
// LDS staging of 16 rows x 148 px x 8 ch f16 (37.9 KB), one __syncthreads.
// Per oc-plane the block writes one contiguous 12-row byte range -> all
// 128B lines fully written (R11 wrote 64B column strips; line partners in
// other blocks -> WRITE 455MB vs 312 ideal). 54 compute units (rowpair x
// 9 x-tiles) ordered tiles-fastest so a row's 9 strips store back-to-back.
// x-halo eliminated; y-halo neighbors same-XCD via chunked swizzle.
// R13's lesson: keep live state small - Bf[5][2] + Wp[6][2] + 2 C vecs only.

#define IH 142
#define IW 142
#define OH 138
#define OW 138
#define SROWS 16
#define PXP 148                 // padded px per staged row
#define ROW_H (PXP * 8)         // 1184 halfs per row
#define ROW_D (PXP * 4)         // 592 dwords per row
#define NSLAB 12
#define NWG (NSLAB * 256)       // 3072, divisible by 8
#define CPX (NWG / 8)           // 384

typedef _Float16 f16x8 __attribute__((ext_vector_type(8)));
typedef float f32x4 __attribute__((ext_vector_type(4)));
typedef unsigned int u32x4 __attribute__((ext_vector_type(4)));

// WIDX[oc][c] = src*64 + block-index, or -1. src 0=w3(6,3,5,5) 1=w4(9,4,5,5)
// 2=w6(1,6,5,5); weight elem = blk*25 + dy*5 + dx.
__device__ __constant__ const short WIDX16[16][6] = {
  {   0,    1,    2,   -1,   -1,   -1},   // oc0  {0,1,2}
  {  -1,    3,    4,    5,   -1,   -1},   // oc1  {1,2,3}
  {  -1,   -1,    6,    7,    8,   -1},   // oc2  {2,3,4}
  {  -1,   -1,   -1,    9,   10,   11},   // oc3  {3,4,5}
  {  12,   -1,   -1,   -1,   13,   14},   // oc4  {0,4,5}
  {  15,   16,   -1,   -1,   -1,   17},   // oc5  {0,1,5}
  {64+0, 64+1, 64+2, 64+3,   -1,   -1},   // oc6  {0,1,2,3}
  {  -1, 64+4, 64+5, 64+6, 64+7,   -1},   // oc7  {1,2,3,4}
  {  -1,   -1, 64+8, 64+9, 64+10, 64+11}, // oc8  {2,3,4,5}
  {64+12,  -1,   -1, 64+13, 64+14, 64+15},// oc9  {0,3,4,5}
  {64+16, 64+17, -1,   -1, 64+18, 64+19}, // oc10 {0,1,4,5}
  {64+20, 64+21, 64+22, -1,  -1, 64+23},  // oc11 {0,1,2,5}
  {64+24, 64+25, -1, 64+26, 64+27,  -1},  // oc12 {0,1,3,4}
  {  -1, 64+28, 64+29, -1, 64+30, 64+31}, // oc13 {1,2,4,5}
  {64+32,  -1, 64+33, 64+34, -1, 64+35},  // oc14 {0,2,3,5}
  {128+0, 128+1, 128+2, 128+3, 128+4, 128+5}, // oc15 {0..5}
};

// prep: per-lane pre-swizzled B fragments, 5 dy x 2 m x 64 lanes x 8 halfs.
// k = m*32 + q*8 + j -> dx = k>>3, c = k&7; zero unless dx<5 && c<6 && consumed.
__global__ void wprep_kernel(const float* __restrict__ w3, const float* __restrict__ w4,
                             const float* __restrict__ w6, _Float16* __restrict__ tab) {
  int t = blockIdx.x * 256 + threadIdx.x;
  if (t >= 5120) return;
  int j = t & 7, lane = (t >> 3) & 63, dm = t >> 9;
  int dy = dm >> 1, m = dm & 1;
  int q = lane >> 4, oc = lane & 15;
  int k = m * 32 + q * 8 + j;
  int dx = k >> 3, c = k & 7;
  float v = 0.f;
  if (c < 6 && dx < 5) {
    int e = WIDX16[oc][c];
    if (e >= 0) {
      int src = e >> 6, blk = e & 63;
      const float* wp = (src == 0) ? w3 : (src == 1) ? w4 : w6;
      v = wp[blk * 25 + dy * 5 + dx];
    }
  }
  tab[t] = (_Float16)v;
}

__device__ __forceinline__ unsigned int pkh(float a, float b) {
  _Float16 ha = (_Float16)a, hb = (_Float16)b;
  unsigned short ua = __builtin_bit_cast(unsigned short, ha);
  unsigned short ub = __builtin_bit_cast(unsigned short, hb);
  return (unsigned int)ua | ((unsigned int)ub << 16);
}

__device__ __forceinline__ float act(float y) {
  const float TS = 1.9235933878519512f;  // 2*(2/3)*log2(e)
  const float e = __builtin_amdgcn_exp2f(y * TS);
  return fmaf(-2.f * 1.7159f, __builtin_amdgcn_rcpf(e + 1.f), 1.7159f);
}

// Block: 256 threads = 4 waves, owns rows y0..y0+11 x FULL width x 16 oc.
// Logical grid: (12 y-slabs, 256 images), XCD-chunk-swizzled.
__global__ __launch_bounds__(256, 4)
void c3_mfma(const float* __restrict__ x,
             const float* __restrict__ b3, const float* __restrict__ b4,
             const float* __restrict__ b6, const _Float16* __restrict__ tab,
             float* __restrict__ out) {
  __shared__ __attribute__((aligned(16))) _Float16 sh[SROWS * ROW_H];  // 37888 B

  const int tid  = threadIdx.x;
  const int lane = tid & 63;
  const int w    = tid >> 6;   // 0..3

  // ---- chunked XCD swizzle: adjacent slabs (same image) -> same XCD ----
  const int hwid = (int)blockIdx.x + NSLAB * (int)blockIdx.z;
  const int swz  = (hwid & 7) * CPX + (hwid >> 3);
  const int sy   = swz % NSLAB;
  const int b    = swz / NSLAB;
  const int y0   = min(sy * 12, OH - 12);   // {0,12,...,120,126}

  const int ocl = lane & 15;   // A row-offset / B col / C col (output channel)
  const int qq  = lane >> 4;

  const float* xb = x + (size_t)b * 6 * IH * IW;
  const size_t PLANE = (size_t)IH * IW;
  unsigned int* __restrict__ shu = (unsigned int*)sh;

  // ---- cooperative staging: 1184 items = (row:16) x (px-pair:74) ----
  // Each item: 6 channel float2 loads -> 8 packed halfs x 2 px -> 2x b128.
  // px2 >= 71 (px 142..147, incl. tile-8 m=1 overrun) and ch 6,7 -> zeros.
  #pragma unroll 2
  for (int it = 0; it < 5; ++it) {
    const int idx = it * 256 + tid;
    if (idx < 1184) {
      const int row = idx / 74;
      const int px2 = idx - row * 74;
      u32x4 d0 = {0u, 0u, 0u, 0u}, d1 = {0u, 0u, 0u, 0u};
      if (px2 < 71) {
        const float* pr = xb + (size_t)(y0 + row) * IW + 2 * px2;
        const float2 v0 = *(const float2*)(pr);
        const float2 v1 = *(const float2*)(pr + PLANE);
        const float2 v2 = *(const float2*)(pr + 2 * PLANE);
        const float2 v3 = *(const float2*)(pr + 3 * PLANE);
        const float2 v4 = *(const float2*)(pr + 4 * PLANE);
        const float2 v5 = *(const float2*)(pr + 5 * PLANE);
        d0[0] = pkh(v0.x, v1.x); d0[1] = pkh(v2.x, v3.x); d0[2] = pkh(v4.x, v5.x);
        d1[0] = pkh(v0.y, v1.y); d1[1] = pkh(v2.y, v3.y); d1[2] = pkh(v4.y, v5.y);
      }
      *(u32x4*)&shu[row * ROW_D + px2 * 8]     = d0;  // px even
      *(u32x4*)&shu[row * ROW_D + px2 * 8 + 4] = d1;  // px odd
    }
  }

  // ---- B fragments + bias (independent; overlap barrier wait) ----
  f16x8 Bf[5][2];
  #pragma unroll
  for (int dy = 0; dy < 5; ++dy)
    #pragma unroll
    for (int m = 0; m < 2; ++m)
      Bf[dy][m] = *(const f16x8*)(tab + ((size_t)((dy * 2 + m) * 64 + lane)) * 8);

  const float bv = (ocl < 6) ? b3[ocl] : (ocl < 15) ? b4[ocl - 6] : b6[0];

  __syncthreads();

  // ---- 54 units = (rowpair rp:6) x (x-tile t:9), tiles fastest so the 9
  // strips of one output row store back-to-back (L2 line merge in-block) ----
  const size_t obase = ((size_t)b * 16 + ocl) * OH;
  #pragma unroll 1
  for (int i = 0; i < 14; ++i) {
    const int u = w + 4 * i;
    if (u >= 54) break;
    const int rp  = u / 9;
    const int t   = u - 9 * rp;
    const int x0t = min(t * 16, OW - 16);   // {0,16,...,112,122}
    const int voff = (x0t + ocl + qq) * 8;  // halfs; +32 for m=1 (dx+4)

    f16x8 Wp[6][2];
    #pragma unroll
    for (int k = 0; k < 6; ++k) {
      Wp[k][0] = *(const f16x8*)&sh[(2 * rp + k) * ROW_H + voff];
      Wp[k][1] = *(const f16x8*)&sh[(2 * rp + k) * ROW_H + voff + 32];
    }

    f32x4 C0 = {bv, bv, bv, bv};
    f32x4 C1 = {bv, bv, bv, bv};
    __builtin_amdgcn_s_setprio(1);
    #pragma unroll
    for (int dy = 0; dy < 5; ++dy) {
      C0 = __builtin_amdgcn_mfma_f32_16x16x32_f16(Wp[dy][0],     Bf[dy][0], C0, 0, 0, 0);
      C1 = __builtin_amdgcn_mfma_f32_16x16x32_f16(Wp[dy + 1][0], Bf[dy][0], C1, 0, 0, 0);
      C0 = __builtin_amdgcn_mfma_f32_16x16x32_f16(Wp[dy][1],     Bf[dy][1], C0, 0, 0, 0);
      C1 = __builtin_amdgcn_mfma_f32_16x16x32_f16(Wp[dy + 1][1], Bf[dy][1], C1, 0, 0, 0);
    }
    __builtin_amdgcn_s_setprio(0);

    {  // stores: rows y0+2rp, +1 (overlapping strips/slabs write identical values)
      float* p0 = out + (obase + (y0 + 2 * rp)) * OW + x0t + qq * 4;
      float* p1 = p0 + OW;
      *(float2*)p0       = make_float2(act(C0[0]), act(C0[1]));
      *(float2*)(p0 + 2) = make_float2(act(C0[2]), act(C0[3]));
      *(float2*)p1       = make_float2(act(C1[0]), act(C1[1]));
      *(float2*)(p1 + 2) = make_float2(act(C1[2]), act(C1[3]));
    }
  }
}

extern "C" void kernel_launch(void* const* d_in, const int* in_sizes, int n_in,
                              void* d_out, int out_size, void* d_ws, size_t ws_size,
                              hipStream_t stream) {
  const float* x  = (const float*)d_in[0];
  const float* w3 = (const float*)d_in[1];
  const float* b3 = (const float*)d_in[2];
  const float* w4 = (const float*)d_in[3];
  const float* b4 = (const float*)d_in[4];
  const float* w6 = (const float*)d_in[5];
  const float* b6 = (const float*)d_in[6];
  float* out = (float*)d_out;
  _Float16* tab = (_Float16*)d_ws;  // 5120 halfs = 10 KiB

  hipLaunchKernelGGL(wprep_kernel, dim3(20), dim3(256), 0, stream, w3, w4, w6, tab);

  dim3 grid(NSLAB, 1, 256);   // y-slabs (12 rows, full width), batch
  hipLaunchKernelGGL(c3_mfma, grid, dim3(256), 0, stream, x, b3, b4, b6, tab, out);
}